// Round 4
// baseline (243.546 us; speedup 1.0000x reference)
//
#include <hip/hip_runtime.h>

#define B_ 4
#define C_ 512
#define H_ 64
#define W_ 208
#define HID_ 512
#define NREG_ 4
#define DS_ 16

// ws layout: delta [B*NREG*C_] fp32 @0 (32KB) | tmp [B*NREG*HID_] fp32 @32KB | swl [B*W] int @64KB

// Blocks 0..255: partial tmp[b,r,d] += sum_{h in 16-chunk} tf[r,b,h]*Wv[r,h,d]
//   grid decomp: r = blk>>6, h-chunk64 = (blk>>3)&7, d-chunk64 = blk&7
// Blocks 256..259: parallel stable counting sort of column labels for b = blk-256
__global__ __launch_bounds__(256) void prepA_kernel(
    const float* __restrict__ tf, const float* __restrict__ Wv,
    const int* __restrict__ mask, float* __restrict__ tmp, int* __restrict__ swl) {
  int blk = blockIdx.x, tid = threadIdx.x;
  if (blk < 256) {
    int r = blk >> 6;
    int h0 = ((blk >> 3) & 7) * 64;
    int d0 = (blk & 7) * 64;
    int g = tid >> 6, dd = tid & 63;
    __shared__ float tf_s[B_][64];
    __shared__ float red[4][B_][64];
    tf_s[g][dd] = tf[(r * B_ + g) * HID_ + h0 + dd];  // g as b, dd as hh
    __syncthreads();
    float acc[B_] = {};
    for (int hh = g * 16; hh < g * 16 + 16; ++hh) {
      float w = Wv[(size_t)(r * HID_ + h0 + hh) * HID_ + d0 + dd];
#pragma unroll
      for (int b = 0; b < B_; ++b) acc[b] += tf_s[b][hh] * w;
    }
#pragma unroll
    for (int b = 0; b < B_; ++b) red[g][b][dd] = acc[b];
    __syncthreads();
    {  // g now indexes b
      float s = red[0][g][dd] + red[1][g][dd] + red[2][g][dd] + red[3][g][dd];
      atomicAdd(&tmp[(g * NREG_ + r) * HID_ + d0 + dd], s);
    }
  } else {
    int b = blk - 256;
    const size_t mb = (size_t)b * (H_ * DS_) * (W_ * DS_);
    int w = tid;
    int l = (w < W_) ? (mask[mb + (size_t)w * DS_] - 1) : -1;
    int wave = tid >> 6, lane = tid & 63;
    unsigned long long bal[NREG_];
    __shared__ int wcnt[4][NREG_];
#pragma unroll
    for (int r = 0; r < NREG_; ++r) bal[r] = __ballot(l == r);
    if (lane < NREG_) wcnt[wave][lane] = __popcll(bal[lane]);
    __syncthreads();
    if (w < W_) {
      int pos = 0;
#pragma unroll
      for (int q = 0; q < NREG_; ++q) {
        int tot = wcnt[0][q] + wcnt[1][q] + wcnt[2][q] + wcnt[3][q];
        if (q < l) pos += tot;
      }
#pragma unroll
      for (int v = 0; v < 4; ++v)
        if (v < wave) pos += wcnt[v][l];
      pos += __popcll(bal[l] & ((1ull << lane) - 1ull));
      swl[b * W_ + pos] = w | (l << 16);
    }
  }
}

// delta[b,r,c] += sum_{d in 16-chunk} tmp[b,r,d]*Wo[r,d,c]; same decomp as prepA
__global__ __launch_bounds__(256) void prepB_kernel(
    const float* __restrict__ tmp, const float* __restrict__ Wo,
    float* __restrict__ delta) {
  int blk = blockIdx.x, tid = threadIdx.x;
  int r = blk >> 6;
  int d0 = ((blk >> 3) & 7) * 64;
  int c0 = (blk & 7) * 64;
  int g = tid >> 6, cc = tid & 63;
  __shared__ float tmp_s[B_][64];
  __shared__ float red[4][B_][64];
  tmp_s[g][cc] = tmp[(g * NREG_ + r) * HID_ + d0 + cc];  // g as b, cc as dd
  __syncthreads();
  float acc[B_] = {};
  for (int dd = g * 16; dd < g * 16 + 16; ++dd) {
    float w = Wo[(size_t)(r * HID_ + d0 + dd) * C_ + c0 + cc];
#pragma unroll
    for (int b = 0; b < B_; ++b) acc[b] += tmp_s[b][dd] * w;
  }
#pragma unroll
  for (int b = 0; b < B_; ++b) red[g][b][cc] = acc[b];
  __syncthreads();
  {  // g now indexes b
    float s = red[0][g][cc] + red[1][g][cc] + red[2][g][cc] + red[3][g][cc];
    atomicAdd(&delta[(g * NREG_ + r) * C_ + c0 + cc], s);
  }
}

// Barrier-free streaming gather: one block per (b,c) plane (H_*W_ = 13312 el).
// The column permutation stays within an 832B row -> 4B gather loads are
// L1-line-coalesced; no LDS tile, no vmcnt(0) barrier in the hot loop.
#define NCHUNK_ (H_ * W_ / 4)   // 3328 float4 per block
#define RCH_ (W_ / 4)           // 52 float4 per row
__global__ __launch_bounds__(256) void apply_kernel(
    const float* __restrict__ img, const float* __restrict__ delta,
    const int* __restrict__ swl, float* __restrict__ out) {
  int blk = blockIdx.x;
  int b = blk >> 9;          // / C_
  int c = blk & (C_ - 1);
  int tid = threadIdx.x;
  __shared__ int swl_s[W_];
  __shared__ float dsel_s[NREG_];
  if (tid < W_) swl_s[tid] = swl[b * W_ + tid];
  if (tid < NREG_) dsel_s[tid] = delta[(b * NREG_ + tid) * C_ + c];
  __syncthreads();
  float d0 = dsel_s[0], d1 = dsel_s[1], d2 = dsel_s[2], d3 = dsel_s[3];
  const float* src = img + (size_t)blk * (H_ * W_);
  float4* dst = (float4*)(out + (size_t)blk * (H_ * W_));
  for (int i = tid; i < NCHUNK_; i += 256) {
    int h = i / RCH_;
    int j = i - h * RCH_;
    const float* row = src + h * W_;
    float res[4];
#pragma unroll
    for (int k = 0; k < 4; ++k) {
      int pl = swl_s[j * 4 + k];
      int s = pl & 0xFFFF;
      int r = pl >> 16;
      float dv = (r == 0) ? d0 : (r == 1) ? d1 : (r == 2) ? d2 : d3;
      res[k] = row[s] + dv;
    }
    dst[i] = make_float4(res[0], res[1], res[2], res[3]);
  }
}

extern "C" void kernel_launch(void* const* d_in, const int* in_sizes, int n_in,
                              void* d_out, int out_size, void* d_ws, size_t ws_size,
                              hipStream_t stream) {
  const float* img  = (const float*)d_in[0];   // image_feature (B,C,H,W) fp32
  const float* tf   = (const float*)d_in[1];   // text_feat (NREG,B,HID) fp32
  const int*   mask = (const int*)d_in[2];     // text_mask (B,1,H*DS,W*DS) int32
  // d_in[3] = Wq (unused), d_in[4] = Wk (unused)
  const float* Wv   = (const float*)d_in[5];   // (NREG,HID,HID) fp32
  const float* Wo   = (const float*)d_in[6];   // (NREG,HID,C) fp32
  float* delta = (float*)d_ws;
  float* tmp   = (float*)((char*)d_ws + 32768);
  int*   swl   = (int*)((char*)d_ws + 65536);
  float* out   = (float*)d_out;

  hipMemsetAsync(d_ws, 0, 65536, stream);  // zero delta + tmp (atomic accumulators)
  prepA_kernel<<<260, 256, 0, stream>>>(tf, Wv, mask, tmp, swl);
  prepB_kernel<<<256, 256, 0, stream>>>(tmp, Wo, delta);
  apply_kernel<<<B_ * C_, 256, 0, stream>>>(img, delta, swl, out);
}

// Round 5
// 237.719 us; speedup vs baseline: 1.0245x; 1.0245x over previous
//
#include <hip/hip_runtime.h>

#define B_ 4
#define C_ 512
#define H_ 64
#define W_ 208
#define HID_ 512
#define NREG_ 4
#define DS_ 16

// ws layout: delta [B*NREG*C_] fp32 @0 (32KB) | tmp [B*NREG*HID_] fp32 @32KB | swl [B*W] int @64KB

// Blocks 0..255: partial tmp[b,r,d] += sum_{h in 16-chunk} tf[r,b,h]*Wv[r,h,d]
// Blocks 256..259: parallel stable counting sort of column labels for b = blk-256
__global__ __launch_bounds__(256) void prepA_kernel(
    const float* __restrict__ tf, const float* __restrict__ Wv,
    const int* __restrict__ mask, float* __restrict__ tmp, int* __restrict__ swl) {
  int blk = blockIdx.x, tid = threadIdx.x;
  if (blk < 256) {
    int r = blk >> 6;
    int h0 = ((blk >> 3) & 7) * 64;
    int d0 = (blk & 7) * 64;
    int g = tid >> 6, dd = tid & 63;
    __shared__ float tf_s[B_][64];
    __shared__ float red[4][B_][64];
    tf_s[g][dd] = tf[(r * B_ + g) * HID_ + h0 + dd];  // g as b, dd as hh
    __syncthreads();
    float acc[B_] = {};
    for (int hh = g * 16; hh < g * 16 + 16; ++hh) {
      float w = Wv[(size_t)(r * HID_ + h0 + hh) * HID_ + d0 + dd];
#pragma unroll
      for (int b = 0; b < B_; ++b) acc[b] += tf_s[b][hh] * w;
    }
#pragma unroll
    for (int b = 0; b < B_; ++b) red[g][b][dd] = acc[b];
    __syncthreads();
    {  // g now indexes b
      float s = red[0][g][dd] + red[1][g][dd] + red[2][g][dd] + red[3][g][dd];
      atomicAdd(&tmp[(g * NREG_ + r) * HID_ + d0 + dd], s);
    }
  } else {
    int b = blk - 256;
    const size_t mb = (size_t)b * (H_ * DS_) * (W_ * DS_);
    int w = tid;
    int l = (w < W_) ? (mask[mb + (size_t)w * DS_] - 1) : -1;
    int wave = tid >> 6, lane = tid & 63;
    unsigned long long bal[NREG_];
    __shared__ int wcnt[4][NREG_];
#pragma unroll
    for (int r = 0; r < NREG_; ++r) bal[r] = __ballot(l == r);
    if (lane < NREG_) wcnt[wave][lane] = __popcll(bal[lane]);
    __syncthreads();
    if (w < W_) {
      int pos = 0;
#pragma unroll
      for (int q = 0; q < NREG_; ++q) {
        int tot = wcnt[0][q] + wcnt[1][q] + wcnt[2][q] + wcnt[3][q];
        if (q < l) pos += tot;
      }
#pragma unroll
      for (int v = 0; v < 4; ++v)
        if (v < wave) pos += wcnt[v][l];
      pos += __popcll(bal[l] & ((1ull << lane) - 1ull));
      swl[b * W_ + pos] = w | (l << 16);
    }
  }
}

// delta[b,r,c] += sum_{d in 16-chunk} tmp[b,r,d]*Wo[r,d,c]; same decomp as prepA
__global__ __launch_bounds__(256) void prepB_kernel(
    const float* __restrict__ tmp, const float* __restrict__ Wo,
    float* __restrict__ delta) {
  int blk = blockIdx.x, tid = threadIdx.x;
  int r = blk >> 6;
  int d0 = ((blk >> 3) & 7) * 64;
  int c0 = (blk & 7) * 64;
  int g = tid >> 6, cc = tid & 63;
  __shared__ float tmp_s[B_][64];
  __shared__ float red[4][B_][64];
  tmp_s[g][cc] = tmp[(g * NREG_ + r) * HID_ + d0 + cc];  // g as b, cc as dd
  __syncthreads();
  float acc[B_] = {};
  for (int dd = g * 16; dd < g * 16 + 16; ++dd) {
    float w = Wo[(size_t)(r * HID_ + d0 + dd) * C_ + c0 + cc];
#pragma unroll
    for (int b = 0; b < B_; ++b) acc[b] += tmp_s[b][dd] * w;
  }
#pragma unroll
  for (int b = 0; b < B_; ++b) red[g][b][cc] = acc[b];
  __syncthreads();
  {  // g now indexes b
    float s = red[0][g][cc] + red[1][g][cc] + red[2][g][cc] + red[3][g][cc];
    atomicAdd(&delta[(g * NREG_ + r) * C_ + c0 + cc], s);
  }
}

// One block per (b,c) plane. Each thread owns exactly 13 float4 chunks
// (3328 = 13*256). ALL 52 gather loads are issued into registers before any
// store -> ~13 KB in flight per wave (vs 16 B before). No barrier after
// prologue, no VGPR cap.
#define GITER_ 13
#define RCH_ (W_ / 4)           // 52 float4 per row
__global__ void apply_kernel(
    const float* __restrict__ img, const float* __restrict__ delta,
    const int* __restrict__ swl, float* __restrict__ out) {
  int blk = blockIdx.x;
  int b = blk >> 9;          // / C_
  int c = blk & (C_ - 1);
  int tid = threadIdx.x;
  __shared__ int swl_s[W_];
  __shared__ float dsel_s[NREG_];
  if (tid < W_) swl_s[tid] = swl[b * W_ + tid];
  if (tid < NREG_) dsel_s[tid] = delta[(b * NREG_ + tid) * C_ + c];
  __syncthreads();
  float d0 = dsel_s[0], d1 = dsel_s[1], d2 = dsel_s[2], d3 = dsel_s[3];
  const float* src = img + (size_t)blk * (H_ * W_);
  float4* dst = (float4*)(out + (size_t)blk * (H_ * W_));
  float res[GITER_][4];
#pragma unroll
  for (int g = 0; g < GITER_; ++g) {
    int i = g * 256 + tid;
    int h = i / RCH_;
    int j = i - h * RCH_;
    const float* row = src + h * W_;
#pragma unroll
    for (int k = 0; k < 4; ++k)
      res[g][k] = row[swl_s[j * 4 + k] & 0xFFFF];
  }
#pragma unroll
  for (int g = 0; g < GITER_; ++g) {
    int i = g * 256 + tid;
    int h = i / RCH_;
    int j = i - h * RCH_;
    float4 o;
    float* op = &o.x;
#pragma unroll
    for (int k = 0; k < 4; ++k) {
      int r = swl_s[j * 4 + k] >> 16;
      float dv = (r == 0) ? d0 : (r == 1) ? d1 : (r == 2) ? d2 : d3;
      op[k] = res[g][k] + dv;
    }
    dst[i] = o;
  }
}

extern "C" void kernel_launch(void* const* d_in, const int* in_sizes, int n_in,
                              void* d_out, int out_size, void* d_ws, size_t ws_size,
                              hipStream_t stream) {
  const float* img  = (const float*)d_in[0];   // image_feature (B,C,H,W) fp32
  const float* tf   = (const float*)d_in[1];   // text_feat (NREG,B,HID) fp32
  const int*   mask = (const int*)d_in[2];     // text_mask (B,1,H*DS,W*DS) int32
  // d_in[3] = Wq (unused), d_in[4] = Wk (unused)
  const float* Wv   = (const float*)d_in[5];   // (NREG,HID,HID) fp32
  const float* Wo   = (const float*)d_in[6];   // (NREG,HID,C) fp32
  float* delta = (float*)d_ws;
  float* tmp   = (float*)((char*)d_ws + 32768);
  int*   swl   = (int*)((char*)d_ws + 65536);
  float* out   = (float*)d_out;

  hipMemsetAsync(d_ws, 0, 65536, stream);  // zero delta + tmp (atomic accumulators)
  prepA_kernel<<<260, 256, 0, stream>>>(tf, Wv, mask, tmp, swl);
  prepB_kernel<<<256, 256, 0, stream>>>(tmp, Wo, delta);
  apply_kernel<<<B_ * C_, 256, 0, stream>>>(img, delta, swl, out);
}